// Round 13
// baseline (220.789 us; speedup 1.0000x reference)
//
#include <hip/hip_runtime.h>

#define TSEQ 512
#define HDIM 256
#define NDIM 64
#define LC   48              // conv truncation; tail ~0.909^48 ~ 2e-3 (threshold 0.1)
#define MT   8               // output rows per block
#define HALO (4 * LC)        // 192
#define HROWS (MT + HALO)    // 200

typedef __attribute__((ext_vector_type(4))) float  f32x4;
typedef __attribute__((ext_vector_type(8))) short  s16x8;
typedef __attribute__((ext_vector_type(4))) unsigned short u16x4;
typedef unsigned short us;

#define MFMA16 __builtin_amdgcn_mfma_f32_16x16x32_bf16

__device__ __forceinline__ float wave_red(float v) {
#pragma unroll
    for (int k = 1; k < 64; k <<= 1) v += __shfl_xor(v, k, 64);
    return v;
}
__device__ __forceinline__ float lane_bcast(float v, int l) {
    return __int_as_float(__builtin_amdgcn_readlane(__float_as_int(v), l));
}
__device__ __forceinline__ us f2bf(float f) {
    unsigned u = __float_as_uint(f);
    u += 0x7fffu + ((u >> 16) & 1u);
    return (us)(u >> 16);
}
__device__ __forceinline__ float bf2f(us h) {
    return __uint_as_float(((unsigned)h) << 16);
}
__device__ __forceinline__ int swz(int row, int chunk) {   // byte offset, [row][256] bf16 swizzled
    return row * 512 + (((chunk) ^ (row & 7)) << 4);
}
__device__ __forceinline__ s16x8 pack8(f32x4 a, f32x4 b) {
    s16x8 r;
    r[0] = (short)f2bf(a[0]); r[1] = (short)f2bf(a[1]);
    r[2] = (short)f2bf(a[2]); r[3] = (short)f2bf(a[3]);
    r[4] = (short)f2bf(b[0]); r[5] = (short)f2bf(b[1]);
    r[6] = (short)f2bf(b[2]); r[7] = (short)f2bf(b[3]);
    return r;
}

// one fully-independent block per 8 output rows; no cross-block communication at all
__global__ void __launch_bounds__(512, 2) k_all(
    const float* __restrict__ x, const float* __restrict__ bin,
    const float* __restrict__ bout, const float* __restrict__ A,
    const float* __restrict__ Bm, const float* __restrict__ Cm,
    const float* __restrict__ Dm, const float* __restrict__ Win,
    const float* __restrict__ Wout, float* __restrict__ out)
{
    __shared__ __align__(16) char smem[154496];
    us*    hbuf  = (us*)smem;                    // [<=224][256] bf16 swz : 102400 B (200 valid)
    us*    bibuf = (us*)(smem + 102400);         // [200][64] bf16       :  25600 B
    us*    wl4   = (us*)(smem + 128000);         // [4][48][64] bf16     :  24576 B
    float* cfin  = (float*)(smem + 152576);      // [224] f32            :    896 B
    float* pstat = (float*)(smem + 153472);      // [2][4][16][2] f32    :   1024 B
    // W-build scratch (aliases hbuf; dead before x staging)
    float* As  = (float*)smem;                   // 16384 B
    float* A8s = (float*)(smem + 16384);         // 16384 B
    float* uls = (float*)(smem + 32768);         // [32][64] f32 8192 B

    const int gid = blockIdx.x, tid = threadIdx.x;
    const int lane = tid & 63, wv = tid >> 6;
    const int m = lane & 15, cgq = lane >> 4;
    const int g = wv >> 2, w4 = wv & 3;          // GEMM pair-group / col-group
    const f32x4 z4 = {0.f, 0.f, 0.f, 0.f};
    const int b = gid >> 6, tb = gid & 63, t0 = tb * MT;

    // ================= Phase W: conv kernel w_j = (A^T)^j Cbar_l (redundant per block) ====
    float cbv = 0.f;
    if (wv < 4) {               // Cbar for layer wv
        const float* cp = Cm + (size_t)wv * HDIM * NDIM + lane;
        float s0 = 0.f, s1 = 0.f, s2 = 0.f, s3 = 0.f;
        for (int h = 0; h < HDIM; h += 4) {
            s0 += cp[(h + 0) * NDIM]; s1 += cp[(h + 1) * NDIM];
            s2 += cp[(h + 2) * NDIM]; s3 += cp[(h + 3) * NDIM];
        }
        cbv = ((s0 + s1) + (s2 + s3)) * (1.0f / HDIM);
    } else {                    // waves 4-7: load A
        int t = tid - 256;
        for (int q = t; q < 1024; q += 256) ((f32x4*)As)[q] = ((const f32x4*)A)[q];
    }
    __syncthreads();
    if (wv < 4) {               // seeds (A^T)^s cbar, s=0..7
        float u = cbv;
        uls[(wv * 8 + 0) * 64 + lane] = u;
#pragma unroll 1
        for (int s = 1; s < 8; ++s) {
            float p0 = 0.f, p1 = 0.f, p2 = 0.f, p3 = 0.f;
#pragma unroll
            for (int k = 0; k < 64; k += 4) {
                p0 += As[(k + 0) * 64 + lane] * lane_bcast(u, k + 0);
                p1 += As[(k + 1) * 64 + lane] * lane_bcast(u, k + 1);
                p2 += As[(k + 2) * 64 + lane] * lane_bcast(u, k + 2);
                p3 += As[(k + 3) * 64 + lane] * lane_bcast(u, k + 3);
            }
            u = (p0 + p1) + (p2 + p3);
            uls[(wv * 8 + s) * 64 + lane] = u;
        }
    } else {                    // A2 = A*A -> A8s
        int t = tid - 256;
        int r = t >> 2, c0 = (t & 3) * 16;
        f32x4 a0 = z4, a1 = z4, a2 = z4, a3 = z4;
        for (int k = 0; k < 64; ++k) {
            float av = As[r * 64 + k];
            const f32x4* bp = (const f32x4*)(As + k * 64 + c0);
            a0 += av * bp[0]; a1 += av * bp[1]; a2 += av * bp[2]; a3 += av * bp[3];
        }
        f32x4* dp = (f32x4*)(A8s + r * 64 + c0);
        dp[0] = a0; dp[1] = a1; dp[2] = a2; dp[3] = a3;
    }
    __syncthreads();
    {   // A4 = A2*A2 -> As
        int r = tid >> 3, c0 = (tid & 7) * 8;
        f32x4 a0 = z4, a1 = z4;
        for (int k = 0; k < 64; ++k) {
            float av = A8s[r * 64 + k];
            const f32x4* bp = (const f32x4*)(A8s + k * 64 + c0);
            a0 += av * bp[0]; a1 += av * bp[1];
        }
        __syncthreads();
        *(f32x4*)(As + r * 64 + c0) = a0;
        *(f32x4*)(As + r * 64 + c0 + 4) = a1;
    }
    __syncthreads();
    {   // A8 = A4*A4 -> A8s
        int r = tid >> 3, c0 = (tid & 7) * 8;
        f32x4 a0 = z4, a1 = z4;
        for (int k = 0; k < 64; ++k) {
            float av = As[r * 64 + k];
            const f32x4* bp = (const f32x4*)(As + k * 64 + c0);
            a0 += av * bp[0]; a1 += av * bp[1];
        }
        __syncthreads();
        *(f32x4*)(A8s + r * 64 + c0) = a0;
        *(f32x4*)(A8s + r * 64 + c0 + 4) = a1;
    }
    __syncthreads();
    {   // chains: parity wv, all 4 layers; w -> wl4 (bf16)
#pragma unroll 1
        for (int l = 0; l < 4; ++l) {
            float u = uls[(l * 8 + wv) * 64 + lane];
#pragma unroll 1
            for (int k6 = 0; k6 < 6; ++k6) {
                wl4[(l * 48 + wv + 8 * k6) * 64 + lane] = f2bf(u);
                if (k6 < 5) {
                    float n0 = 0.f, n1 = 0.f, n2 = 0.f, n3 = 0.f;
#pragma unroll
                    for (int k = 0; k < 64; k += 4) {
                        n0 += A8s[(k + 0) * 64 + lane] * lane_bcast(u, k + 0);
                        n1 += A8s[(k + 1) * 64 + lane] * lane_bcast(u, k + 1);
                        n2 += A8s[(k + 2) * 64 + lane] * lane_bcast(u, k + 2);
                        n3 += A8s[(k + 3) * 64 + lane] * lane_bcast(u, k + 3);
                    }
                    u = (n0 + n1) + (n2 + n3);
                }
            }
        }
    }
    __syncthreads();

    // ================= stage x rows [t0-192, t0+8) -> hbuf (bf16 swz) =================
    {
        const float* xb = x + (size_t)b * TSEQ * HDIM;
#pragma unroll 1
        for (int q = tid; q < HROWS * 64; q += 512) {
            int rel = q >> 6, c4 = q & 63;
            int gt = t0 - HALO + rel;
            f32x4 v = (gt >= 0) ? ((const f32x4*)(xb + (size_t)gt * HDIM))[c4] : z4;
            u16x4 pk; pk[0] = f2bf(v[0]); pk[1] = f2bf(v[1]); pk[2] = f2bf(v[2]); pk[3] = f2bf(v[3]);
            *(u16x4*)((char*)hbuf + swz(rel, c4 >> 1) + (c4 & 1) * 8) = pk;
        }
    }
    __syncthreads();

    // ================= in-GEMM: h0 = x @ Win^T + bin (in-place, 32-row pairs) ==========
#pragma unroll 1
    for (int pi = 0; pi < 7; ++pi) {
        const int rel0p = pi * 32 + g * 16;
        f32x4 a0 = z4, a1 = z4, a2 = z4, a3 = z4;
        const float* B0 = Win + (size_t)(w4 * 64 + m) * HDIM;
#pragma unroll
        for (int ks = 0; ks < 8; ++ks) {
            s16x8 av = *(const s16x8*)((const char*)hbuf + swz(rel0p + m, ks * 4 + cgq));
            const float* p0 = B0 + ks * 32 + cgq * 8;
            a0 = MFMA16(av, pack8(*(const f32x4*)p0, *(const f32x4*)(p0 + 4)), a0, 0, 0, 0);
            const float* p1 = p0 + 16 * HDIM;
            a1 = MFMA16(av, pack8(*(const f32x4*)p1, *(const f32x4*)(p1 + 4)), a1, 0, 0, 0);
            const float* p2 = p0 + 32 * HDIM;
            a2 = MFMA16(av, pack8(*(const f32x4*)p2, *(const f32x4*)(p2 + 4)), a2, 0, 0, 0);
            const float* p3 = p0 + 48 * HDIM;
            a3 = MFMA16(av, pack8(*(const f32x4*)p3, *(const f32x4*)(p3 + 4)), a3, 0, 0, 0);
        }
        __syncthreads();        // all reads of this pair's rows done before in-place write
#pragma unroll
        for (int nt = 0; nt < 4; ++nt) {
            int col = w4 * 64 + nt * 16 + m;
            float bi = bin[col];
            f32x4 av_ = nt == 0 ? a0 : nt == 1 ? a1 : nt == 2 ? a2 : a3;
#pragma unroll
            for (int reg = 0; reg < 4; ++reg) {
                int row = rel0p + cgq * 4 + reg;
                if (row < HROWS)
                    *(us*)((char*)hbuf + swz(row, col >> 3) + (col & 7) * 2) = f2bf(av_[reg] + bi);
            }
        }
    }
    __syncthreads();

    // ================= layer loop (all local) =================
#pragma unroll 1
    for (int l = 0; l < 4; ++l) {
        const int sIn = 48 * l, rowsIn = HROWS - sIn;
        const int sOut = sIn + 48, rowsOut = HROWS - sOut;
        const int npB = (rowsIn + 31) >> 5;
        const int npD = (rowsOut + 31) >> 5;
        const int nch = rowsOut >> 2;

        // ---- B-proj: binp^l = h^l @ B_l^T -> bibuf (bf16) ----
#pragma unroll 1
        for (int pi = 0; pi < npB; ++pi) {
            const int rel0p = sIn + pi * 32 + g * 16;
            f32x4 ab = z4;
            const float* B0 = Bm + (size_t)l * NDIM * HDIM + (size_t)(w4 * 16 + m) * HDIM;
#pragma unroll
            for (int ks = 0; ks < 8; ++ks) {
                s16x8 av = *(const s16x8*)((const char*)hbuf + swz(rel0p + m, ks * 4 + cgq));
                const float* p0 = B0 + ks * 32 + cgq * 8;
                ab = MFMA16(av, pack8(*(const f32x4*)p0, *(const f32x4*)(p0 + 4)), ab, 0, 0, 0);
            }
#pragma unroll
            for (int reg = 0; reg < 4; ++reg) {
                int row = rel0p + cgq * 4 + reg;
                if (row < HROWS) {
                    int gt = t0 - HALO + row;
                    bibuf[row * 64 + w4 * 16 + m] = (gt >= 0) ? f2bf(ab[reg]) : (us)0;
                }
            }
        }
        __syncthreads();

        // ---- conv: c[r] = sum_j w_j . binp[r-1-j], 4-row rolling chunks ----
#pragma unroll 1
        for (int ch = wv; ch < nch; ch += 8) {
            const int r0 = sOut + ch * 4;
            float c0 = 0.f, c1 = 0.f, c2 = 0.f, c3 = 0.f;
            float v0 = bf2f(bibuf[(r0 - 1) * 64 + lane]);
            float v1 = bf2f(bibuf[(r0 + 0) * 64 + lane]);
            float v2 = bf2f(bibuf[(r0 + 1) * 64 + lane]);
            float v3 = bf2f(bibuf[(r0 + 2) * 64 + lane]);
            const us* wp = wl4 + (size_t)l * 48 * 64 + lane;
#pragma unroll
            for (int j = 0; j < LC; ++j) {
                float wj = bf2f(wp[j * 64]);
                c0 += wj * v0; c1 += wj * v1; c2 += wj * v2; c3 += wj * v3;
                v3 = v2; v2 = v1; v1 = v0;
                if (j < LC - 1) v0 = bf2f(bibuf[(r0 - 2 - j) * 64 + lane]);
            }
            c0 = wave_red(c0); c1 = wave_red(c1); c2 = wave_red(c2); c3 = wave_red(c3);
            if (lane == 0) { cfin[r0] = c0; cfin[r0 + 1] = c1; cfin[r0 + 2] = c2; cfin[r0 + 3] = c3; }
        }
        __syncthreads();

        // ---- D-GEMM + gelu + residual + LN (in-place h^l -> h^{l+1}) ----
#pragma unroll 1
        for (int pi = 0; pi < npD; ++pi) {
            const int rel0p = sOut + pi * 32 + g * 16;
            f32x4 a0 = z4, a1 = z4, a2 = z4, a3 = z4;
            const float* D0 = Dm + (size_t)l * HDIM * HDIM + (size_t)(w4 * 64 + m) * HDIM;
#pragma unroll
            for (int ks = 0; ks < 8; ++ks) {
                s16x8 av = *(const s16x8*)((const char*)hbuf + swz(rel0p + m, ks * 4 + cgq));
                const float* p0 = D0 + ks * 32 + cgq * 8;
                a0 = MFMA16(av, pack8(*(const f32x4*)p0, *(const f32x4*)(p0 + 4)), a0, 0, 0, 0);
                const float* p1 = p0 + 16 * HDIM;
                a1 = MFMA16(av, pack8(*(const f32x4*)p1, *(const f32x4*)(p1 + 4)), a1, 0, 0, 0);
                const float* p2 = p0 + 32 * HDIM;
                a2 = MFMA16(av, pack8(*(const f32x4*)p2, *(const f32x4*)(p2 + 4)), a2, 0, 0, 0);
                const float* p3 = p0 + 48 * HDIM;
                a3 = MFMA16(av, pack8(*(const f32x4*)p3, *(const f32x4*)(p3 + 4)), a3, 0, 0, 0);
            }
            // combine: + c, gelu, + residual (residual read BEFORE in-place write)
            f32x4 cf;
#pragma unroll
            for (int reg = 0; reg < 4; ++reg) cf[reg] = cfin[rel0p + cgq * 4 + reg];
            f32x4 o0, o1, o2, o3;
#pragma unroll
            for (int nt = 0; nt < 4; ++nt) {
                int col = w4 * 64 + nt * 16 + m;
                f32x4 av_ = nt == 0 ? a0 : nt == 1 ? a1 : nt == 2 ? a2 : a3;
                f32x4 ov;
#pragma unroll
                for (int reg = 0; reg < 4; ++reg) {
                    int row = rel0p + cgq * 4 + reg;
                    float val = av_[reg] + cf[reg];
                    float ge = 0.5f * val * (1.0f + erff(val * 0.70710678118654752f));
                    float rsd = bf2f(*(const us*)((const char*)hbuf + swz(row, col >> 3) + (col & 7) * 2));
                    ov[reg] = ge + rsd;
                }
                if (nt == 0) o0 = ov; else if (nt == 1) o1 = ov; else if (nt == 2) o2 = ov; else o3 = ov;
            }
            // LN partials: sum over this wave's 64 cols, reduce across 16 m-lanes
            f32x4 sl = o0 + o1 + o2 + o3;
            f32x4 sq = o0 * o0 + o1 * o1 + o2 * o2 + o3 * o3;
#pragma unroll
            for (int reg = 0; reg < 4; ++reg) {
                float s_ = sl[reg], q_ = sq[reg];
                s_ += __shfl_xor(s_, 1, 64); q_ += __shfl_xor(q_, 1, 64);
                s_ += __shfl_xor(s_, 2, 64); q_ += __shfl_xor(q_, 2, 64);
                s_ += __shfl_xor(s_, 4, 64); q_ += __shfl_xor(q_, 4, 64);
                s_ += __shfl_xor(s_, 8, 64); q_ += __shfl_xor(q_, 8, 64);
                if (m == 0) {
                    int idx = ((g * 4 + w4) * 16 + cgq * 4 + reg) * 2;
                    pstat[idx] = s_; pstat[idx + 1] = q_;
                }
            }
            __syncthreads();
            // LN finalize + write h^{l+1}
#pragma unroll
            for (int reg = 0; reg < 4; ++reg) {
                int rr = cgq * 4 + reg;
                int row = rel0p + rr;
                float s = 0.f, q = 0.f;
#pragma unroll
                for (int wp4 = 0; wp4 < 4; ++wp4) {
                    int idx = ((g * 4 + wp4) * 16 + rr) * 2;
                    s += pstat[idx]; q += pstat[idx + 1];
                }
                float mn = s * (1.0f / HDIM);
                float var = q * (1.0f / HDIM) - mn * mn;
                float rsq = rsqrtf(var + 1e-5f);
                if (l == 3) { float vz = var * rsq * rsq; rsq *= rsqrtf(vz + 1e-5f); }
                if (row < HROWS) {
#pragma unroll
                    for (int nt = 0; nt < 4; ++nt) {
                        int col = w4 * 64 + nt * 16 + m;
                        f32x4 ov = nt == 0 ? o0 : nt == 1 ? o1 : nt == 2 ? o2 : o3;
                        *(us*)((char*)hbuf + swz(row, col >> 3) + (col & 7) * 2) =
                            f2bf((ov[reg] - mn) * rsq);
                    }
                }
            }
            __syncthreads();    // pstat reuse + write/read ordering for next pair
        }
    }

    // ================= out-GEMM: out = z2 @ Wout^T + bout (rows rel 192..199) ==========
    {
        f32x4 q0 = z4, q1 = z4;
        const float* W0 = Wout + (size_t)(wv * 32 + m) * HDIM;
        const float* W1 = W0 + (size_t)16 * HDIM;
#pragma unroll
        for (int ks = 0; ks < 8; ++ks) {
            s16x8 av = *(const s16x8*)((const char*)hbuf + swz(HALO + m, ks * 4 + cgq));
            const float* p0 = W0 + ks * 32 + cgq * 8;
            q0 = MFMA16(av, pack8(*(const f32x4*)p0, *(const f32x4*)(p0 + 4)), q0, 0, 0, 0);
            const float* p1 = W1 + ks * 32 + cgq * 8;
            q1 = MFMA16(av, pack8(*(const f32x4*)p1, *(const f32x4*)(p1 + 4)), q1, 0, 0, 0);
        }
#pragma unroll
        for (int nt = 0; nt < 2; ++nt) {
            int col = wv * 32 + nt * 16 + m;
            float bo = bout[col];
            f32x4 qv = nt == 0 ? q0 : q1;
#pragma unroll
            for (int reg = 0; reg < 4; ++reg) {
                int row = cgq * 4 + reg;
                if (row < MT)
                    out[(size_t)(b * TSEQ + t0 + row) * HDIM + col] = qv[reg] + bo;
            }
        }
    }
}

extern "C" void kernel_launch(void* const* d_in, const int* in_sizes, int n_in,
                              void* d_out, int out_size, void* d_ws, size_t ws_size,
                              hipStream_t stream) {
    (void)in_sizes; (void)n_in; (void)out_size; (void)d_ws; (void)ws_size;
    const float* x    = (const float*)d_in[0];
    const float* Win  = (const float*)d_in[1];
    const float* bin  = (const float*)d_in[2];
    const float* Wout = (const float*)d_in[3];
    const float* bout = (const float*)d_in[4];
    const float* A    = (const float*)d_in[5];
    const float* Bm   = (const float*)d_in[6];
    const float* Cm   = (const float*)d_in[7];
    const float* Dm   = (const float*)d_in[8];
    float* out = (float*)d_out;

    k_all<<<256, 512, 0, stream>>>(x, bin, bout, A, Bm, Cm, Dm, Win, Wout, out);
}

// Round 14
// 87.913 us; speedup vs baseline: 2.5114x; 2.5114x over previous
//
#include <hip/hip_runtime.h>

#define TSEQ 512
#define HDIM 256
#define NDIM 64
#define LC   48        // conv truncation; tail ~0.909^48 ~ 2e-3 (threshold 0.1)
#define MT   16        // t-rows per tile
#define NWB  64        // work blocks (each owns 2 tiles); block 64 = W block
#define NTILE 128      // total tiles

typedef __attribute__((ext_vector_type(4))) float  f32x4;
typedef __attribute__((ext_vector_type(8))) short  s16x8;
typedef __attribute__((ext_vector_type(4))) unsigned short u16x4;
typedef unsigned long long u64;
typedef unsigned short us;

#define MFMA16 __builtin_amdgcn_mfma_f32_16x16x32_bf16

__device__ __forceinline__ float lane_bcast(float v, int l) {
    return __int_as_float(__builtin_amdgcn_readlane(__float_as_int(v), l));
}
__device__ __forceinline__ us f2bf(float f) {
    unsigned u = __float_as_uint(f);
    u += 0x7fffu + ((u >> 16) & 1u);
    return (us)(u >> 16);
}
__device__ __forceinline__ float bf2f(us h) {
    return __uint_as_float(((unsigned)h) << 16);
}
__device__ __forceinline__ int swz(int row, int chunk) {   // 16B chunk in [16][256] bf16 tile
    return row * 512 + (((chunk) ^ (row & 7)) << 4);
}
__device__ __forceinline__ void st_mall(float* p, float v) {
    __hip_atomic_store(p, v, __ATOMIC_RELAXED, __HIP_MEMORY_SCOPE_AGENT);
}
__device__ __forceinline__ u64 ld_mall8(const u64* p) {
    return __hip_atomic_load(p, __ATOMIC_RELAXED, __HIP_MEMORY_SCOPE_AGENT);
}
__device__ __forceinline__ void flag_set(unsigned* f) {
    __hip_atomic_store(f, 1u, __ATOMIC_RELAXED, __HIP_MEMORY_SCOPE_AGENT);
}
__device__ __forceinline__ void flag_wait(const unsigned* f) {
    while (__hip_atomic_load(f, __ATOMIC_RELAXED, __HIP_MEMORY_SCOPE_AGENT) == 0u)
        __builtin_amdgcn_s_sleep(1);
}

// ============ k_prep: weights f32->bf16 (0..127), Cbar+flags (128), A^8 (129) ============
__global__ void __launch_bounds__(256) k_prep(
    const float* __restrict__ Win, const float* __restrict__ Wout,
    const float* __restrict__ Bm, const float* __restrict__ Dm,
    const float* __restrict__ Cm, const float* __restrict__ A,
    us* __restrict__ Win_bf, us* __restrict__ Wout_bf,
    us* __restrict__ Bm_bf, us* __restrict__ Dm_bf,
    float* __restrict__ cbar_g, float* __restrict__ wA8,
    unsigned* __restrict__ flags)
{
    __shared__ __align__(16) float Pa[4096];
    __shared__ __align__(16) float Pb[4096];
    const int gid = blockIdx.x, tid = threadIdx.x;

    if (gid < 128) {
        for (int q = gid * 256 + tid; q < 114688; q += 32768) {
            const float* s; us* d; int off;
            if (q < 16384)      { s = Win;  d = Win_bf;  off = q; }
            else if (q < 32768) { s = Wout; d = Wout_bf; off = q - 16384; }
            else if (q < 49152) { s = Bm;   d = Bm_bf;   off = q - 32768; }
            else                { s = Dm;   d = Dm_bf;   off = q - 49152; }
            f32x4 v = ((const f32x4*)s)[off];
            u16x4 p; p[0] = f2bf(v[0]); p[1] = f2bf(v[1]); p[2] = f2bf(v[2]); p[3] = f2bf(v[3]);
            ((u16x4*)d)[off] = p;
        }
        return;
    }
    if (gid == 128) {
        for (int i = tid; i < 4 + 4 * NTILE; i += 256)
            __hip_atomic_store(&flags[i], 0u, __ATOMIC_RELAXED, __HIP_MEMORY_SCOPE_AGENT);
        const int l = tid >> 6, n = tid & 63;
        const float* cp = Cm + (size_t)l * HDIM * NDIM + n;
        float s0 = 0.f, s1 = 0.f, s2 = 0.f, s3 = 0.f;
        for (int h = 0; h < HDIM; h += 4) {
            s0 += cp[(h + 0) * NDIM]; s1 += cp[(h + 1) * NDIM];
            s2 += cp[(h + 2) * NDIM]; s3 += cp[(h + 3) * NDIM];
        }
        cbar_g[tid] = ((s0 + s1) + (s2 + s3)) * (1.0f / HDIM);
        return;
    }
    // gid == 129: A8 = ((A^2)^2)^2 via LDS matmuls
    for (int q = tid; q < 1024; q += 256) ((f32x4*)Pa)[q] = ((const f32x4*)A)[q];
    __syncthreads();
    const int r0 = (tid >> 3) * 2, c0 = (tid & 7) * 8;
    const f32x4 z4 = {0.f, 0.f, 0.f, 0.f};
#pragma unroll 1
    for (int it = 0; it < 3; ++it) {
        const float* S = (it & 1) ? Pb : Pa;
        float*       D = (it & 1) ? Pa : Pb;
        f32x4 s00 = z4, s01 = z4, s10 = z4, s11 = z4;
        for (int k = 0; k < 64; ++k) {
            float a0 = S[r0 * 64 + k], a1 = S[(r0 + 1) * 64 + k];
            f32x4 b0 = *(const f32x4*)(S + k * 64 + c0);
            f32x4 b1 = *(const f32x4*)(S + k * 64 + c0 + 4);
            s00 += a0 * b0; s01 += a0 * b1; s10 += a1 * b0; s11 += a1 * b1;
        }
        *(f32x4*)(D + r0 * 64 + c0) = s00;       *(f32x4*)(D + r0 * 64 + c0 + 4) = s01;
        *(f32x4*)(D + (r0 + 1) * 64 + c0) = s10; *(f32x4*)(D + (r0 + 1) * 64 + c0 + 4) = s11;
        __syncthreads();
    }
    for (int q = tid; q < 1024; q += 256) ((f32x4*)wA8)[q] = ((const f32x4*)Pb)[q];
}

// ============ k_fused: 64 work blocks x 2 tiles + W block ============
__global__ void __launch_bounds__(512, 2) k_fused(
    const float* __restrict__ x, const float* __restrict__ bin,
    const float* __restrict__ bout, const float* __restrict__ A,
    const float* __restrict__ wA8, const float* __restrict__ cbar_g,
    const us* __restrict__ Win_bf, const us* __restrict__ Wout_bf,
    const us* __restrict__ Bm_bf, const us* __restrict__ Dm_bf,
    float* __restrict__ wbuf, float* __restrict__ BiA, float* __restrict__ BiB,
    unsigned* __restrict__ flags, float* __restrict__ out)
{
    __shared__ __align__(16) char smem[63616];
    us*    xlA   = (us*)smem;                    //  8192 B
    us*    xlB   = (us*)(smem + 8192);           //  8192 B
    float* bwinA = (float*)(smem + 16384);       // 16384 B [64][64]
    float* bwinB = (float*)(smem + 32768);       // 16384 B
    float* wlds  = (float*)(smem + 49152);       // 12288 B [48][64]
    float* cfinA = (float*)(smem + 61440);       //    64 B
    float* cfinB = (float*)(smem + 61504);       //    64 B
    float* pstat = (float*)(smem + 61568);       //  2048 B [2][8][16][2]
    // W-block aliases
    float* As  = (float*)smem;                   // 16384 B
    float* A8s = (float*)(smem + 16384);         // 16384 B
    float* uls = (float*)(smem + 32768);         //  8192 B

    const int gid = blockIdx.x, tid = threadIdx.x;
    const int lane = tid & 63, wv = tid >> 6;
    const int m = lane & 15, cgq = lane >> 4;
    const f32x4 z4 = {0.f, 0.f, 0.f, 0.f};

    if (gid == NWB) {
        // ======== W block: seeds over A, chains over A^8 (R10-proven) ========
        for (int q = tid; q < 1024; q += 512) {
            ((f32x4*)As)[q]  = ((const f32x4*)A)[q];
            ((f32x4*)A8s)[q] = ((const f32x4*)wA8)[q];
        }
        __syncthreads();
        if (wv < 4) {
            float u = cbar_g[wv * 64 + lane];
            uls[(wv * 8 + 0) * 64 + lane] = u;
#pragma unroll 1
            for (int s = 1; s < 8; ++s) {
                float p0 = 0.f, p1 = 0.f, p2 = 0.f, p3 = 0.f;
#pragma unroll
                for (int k = 0; k < 64; k += 4) {
                    p0 += As[(k + 0) * 64 + lane] * lane_bcast(u, k + 0);
                    p1 += As[(k + 1) * 64 + lane] * lane_bcast(u, k + 1);
                    p2 += As[(k + 2) * 64 + lane] * lane_bcast(u, k + 2);
                    p3 += As[(k + 3) * 64 + lane] * lane_bcast(u, k + 3);
                }
                u = (p0 + p1) + (p2 + p3);
                uls[(wv * 8 + s) * 64 + lane] = u;
            }
        }
        __syncthreads();
        {   // layer-0 chain first (parity wv)
            float u = uls[wv * 64 + lane];
#pragma unroll 1
            for (int k6 = 0; k6 < 6; ++k6) {
                st_mall(&wbuf[(size_t)(wv + 8 * k6) * 64 + lane], u);
                if (k6 < 5) {
                    float n0 = 0.f;
#pragma unroll
                    for (int k = 0; k < 64; ++k)
                        n0 += A8s[k * 64 + lane] * lane_bcast(u, k);
                    u = n0;
                }
            }
        }
        __syncthreads();
        if (tid == 0) flag_set(&flags[0]);
        {   // layers 1-3 chains interleaved
            float u1 = uls[(8 + wv) * 64 + lane];
            float u2 = uls[(16 + wv) * 64 + lane];
            float u3 = uls[(24 + wv) * 64 + lane];
#pragma unroll 1
            for (int k6 = 0; k6 < 6; ++k6) {
                const int j = wv + 8 * k6;
                st_mall(&wbuf[(size_t)(1 * LC + j) * 64 + lane], u1);
                st_mall(&wbuf[(size_t)(2 * LC + j) * 64 + lane], u2);
                st_mall(&wbuf[(size_t)(3 * LC + j) * 64 + lane], u3);
                if (k6 < 5) {
                    float n1 = 0.f, n2 = 0.f, n3 = 0.f;
#pragma unroll
                    for (int k = 0; k < 64; ++k) {
                        float a = A8s[k * 64 + lane];
                        n1 += a * lane_bcast(u1, k); n2 += a * lane_bcast(u2, k);
                        n3 += a * lane_bcast(u3, k);
                    }
                    u1 = n1; u2 = n2; u3 = n3;
                }
            }
        }
        __syncthreads();
        if (tid < 3) flag_set(&flags[1 + tid]);
        return;
    }

    // ======== work blocks: 2 tiles (batches bA and bA+2), same tb ========
    const int bA = gid >> 5, tb = gid & 31, t0 = tb * MT;
    const int bB = bA + 2;
    const int tileA = bA * 32 + tb, tileB = bB * 32 + tb;
    const size_t growA = (size_t)(bA * TSEQ + t0);
    const size_t growB = (size_t)(bB * TSEQ + t0);

    {   // stage x for both tiles (f32 -> bf16 swizzled)
        const f32x4* gsA = (const f32x4*)(x + growA * HDIM);
        const f32x4* gsB = (const f32x4*)(x + growB * HDIM);
#pragma unroll
        for (int k = 0; k < 2; ++k) {
            int q = tid + k * 512;
            int row = q >> 6, c4 = q & 63;
            f32x4 v = gsA[q];
            u16x4 pk; pk[0] = f2bf(v[0]); pk[1] = f2bf(v[1]); pk[2] = f2bf(v[2]); pk[3] = f2bf(v[3]);
            *(u16x4*)((char*)xlA + swz(row, c4 >> 1) + (c4 & 1) * 8) = pk;
            f32x4 w = gsB[q];
            u16x4 pw; pw[0] = f2bf(w[0]); pw[1] = f2bf(w[1]); pw[2] = f2bf(w[2]); pw[3] = f2bf(w[3]);
            *(u16x4*)((char*)xlB + swz(row, c4 >> 1) + (c4 & 1) * 8) = pw;
        }
    }
    __syncthreads();

    {   // in-GEMM both tiles: h0 = x @ Win^T + bin
        f32x4 hA0 = z4, hA1 = z4, hB0 = z4, hB1 = z4;
        const us* W0 = Win_bf + (size_t)(wv * 32 + m) * HDIM;
        const us* W1 = W0 + (size_t)16 * HDIM;
#pragma unroll
        for (int ks = 0; ks < 8; ++ks) {
            s16x8 avA = *(const s16x8*)((const char*)xlA + swz(m, ks * 4 + cgq));
            s16x8 avB = *(const s16x8*)((const char*)xlB + swz(m, ks * 4 + cgq));
            s16x8 w0 = *(const s16x8*)(W0 + ks * 32 + cgq * 8);
            s16x8 w1 = *(const s16x8*)(W1 + ks * 32 + cgq * 8);
            hA0 = MFMA16(avA, w0, hA0, 0, 0, 0);
            hA1 = MFMA16(avA, w1, hA1, 0, 0, 0);
            hB0 = MFMA16(avB, w0, hB0, 0, 0, 0);
            hB1 = MFMA16(avB, w1, hB1, 0, 0, 0);
        }
        __syncthreads();   // x reads done before overwrite
        const int h0c = wv * 32 + m, h1c = h0c + 16;
        float bi0 = bin[h0c], bi1 = bin[h1c];
#pragma unroll
        for (int reg = 0; reg < 4; ++reg) {
            int trow = cgq * 4 + reg;
            *(us*)((char*)xlA + swz(trow, h0c >> 3) + (h0c & 7) * 2) = f2bf(hA0[reg] + bi0);
            *(us*)((char*)xlA + swz(trow, h1c >> 3) + (h1c & 7) * 2) = f2bf(hA1[reg] + bi1);
            *(us*)((char*)xlB + swz(trow, h0c >> 3) + (h0c & 7) * 2) = f2bf(hB0[reg] + bi0);
            *(us*)((char*)xlB + swz(trow, h1c >> 3) + (h1c & 7) * 2) = f2bf(hB1[reg] + bi1);
        }
    }
    __syncthreads();

    {   // B-proj layer 0: waves 0-3 -> tileA, waves 4-7 -> tileB
        const int tw = (wv < 4) ? wv : wv - 4;
        const us* xls = (wv < 4) ? xlA : xlB;
        const size_t gr = (wv < 4) ? growA : growB;
        f32x4 accb = z4;
        const us* B0 = Bm_bf + (size_t)(tw * 16 + m) * HDIM;
#pragma unroll
        for (int ks = 0; ks < 8; ++ks) {
            s16x8 av = *(const s16x8*)((const char*)xls + swz(m, ks * 4 + cgq));
            s16x8 bv = *(const s16x8*)(B0 + ks * 32 + cgq * 8);
            accb = MFMA16(av, bv, accb, 0, 0, 0);
        }
#pragma unroll
        for (int reg = 0; reg < 4; ++reg)
            st_mall(&BiA[(gr + cgq * 4 + reg) * NDIM + tw * 16 + m], accb[reg]);
    }
    __syncthreads();                // drain binp stores
    if (tid == 0) flag_set(&flags[4 + 0 * NTILE + tileA]);
    if (tid == 1) flag_set(&flags[4 + 0 * NTILE + tileB]);

    // ---------------- layer loop ----------------
#pragma unroll 1
    for (int l = 0; l < 4; ++l) {
        const float* bi = (l & 1) ? BiB : BiA;
        float*       bo = (l & 1) ? BiA : BiB;
        const us* Dl = Dm_bf + (size_t)l * HDIM * HDIM;

        // 1. D-GEMM both tiles (purely local; waits hide under it)
        f32x4 dA0 = z4, dA1 = z4, dB0 = z4, dB1 = z4;
        {
            const us* D0 = Dl + (size_t)(wv * 32 + m) * HDIM;
            const us* D1 = D0 + (size_t)16 * HDIM;
#pragma unroll
            for (int ks = 0; ks < 8; ++ks) {
                s16x8 avA = *(const s16x8*)((const char*)xlA + swz(m, ks * 4 + cgq));
                s16x8 avB = *(const s16x8*)((const char*)xlB + swz(m, ks * 4 + cgq));
                s16x8 b0 = *(const s16x8*)(D0 + ks * 32 + cgq * 8);
                s16x8 b1 = *(const s16x8*)(D1 + ks * 32 + cgq * 8);
                dA0 = MFMA16(avA, b0, dA0, 0, 0, 0);
                dA1 = MFMA16(avA, b1, dA1, 0, 0, 0);
                dB0 = MFMA16(avB, b0, dB0, 0, 0, 0);
                dB1 = MFMA16(avB, b1, dB1, 0, 0, 0);
            }
        }

        // 2. wait: w flag (lane 3), tileA neighbors (lanes 0-2), tileB neighbors (lanes 4-6)
        {
            const unsigned* fp = nullptr;
            if (lane == 3) fp = &flags[l];
            else if (lane < 3 && (tb - 1 - (int)lane) >= 0)
                fp = &flags[4 + l * NTILE + tileA - 1 - lane];
            else if (lane >= 4 && lane < 7 && (tb - 1 - (int)(lane - 4)) >= 0)
                fp = &flags[4 + l * NTILE + tileB - 1 - (lane - 4)];
            if (fp) flag_wait(fp);
        }

        // 3. stage w + both binp windows (MALL 8B)
        {
            const u64* ws8 = (const u64*)(wbuf + (size_t)l * LC * NDIM);
            for (int q = tid; q < LC * NDIM / 2; q += 512)
                ((u64*)wlds)[q] = ld_mall8(&ws8[q]);
            const u64* biA8 = (const u64*)(bi + (size_t)bA * TSEQ * NDIM);
            const u64* biB8 = (const u64*)(bi + (size_t)bB * TSEQ * NDIM);
#pragma unroll
            for (int k = 0; k < 4; ++k) {
                int q = tid + k * 512;
                int r = q >> 5, cc = q & 31;
                int t = t0 - LC + r;
                ((u64*)bwinA)[q] = (t >= 0) ? ld_mall8(&biA8[(size_t)t * 32 + cc]) : 0ull;
                ((u64*)bwinB)[q] = (t >= 0) ? ld_mall8(&biB8[(size_t)t * 32 + cc]) : 0ull;
            }
        }
        __syncthreads();

        {   // 4. conv: 2 rows/wave, both tiles
            const int r0 = wv * 2;
            float cA0 = 0.f, cA1 = 0.f, cB0 = 0.f, cB1 = 0.f;
            float vA0 = bwinA[(LC - 1 + r0) * NDIM + lane];
            float vA1 = bwinA[(LC + r0) * NDIM + lane];
            float vB0 = bwinB[(LC - 1 + r0) * NDIM + lane];
            float vB1 = bwinB[(LC + r0) * NDIM + lane];
#pragma unroll
            for (int j = 0; j < LC; ++j) {
                float wj = wlds[j * NDIM + lane];
                cA0 += wj * vA0; cA1 += wj * vA1;
                cB0 += wj * vB0; cB1 += wj * vB1;
                vA1 = vA0; vB1 = vB0;
                int nr = LC - 2 + r0 - j; nr = nr < 0 ? 0 : nr;
                vA0 = bwinA[nr * NDIM + lane];
                vB0 = bwinB[nr * NDIM + lane];
            }
#pragma unroll
            for (int k = 1; k < 64; k <<= 1) {
                cA0 += __shfl_xor(cA0, k, 64); cA1 += __shfl_xor(cA1, k, 64);
                cB0 += __shfl_xor(cB0, k, 64); cB1 += __shfl_xor(cB1, k, 64);
            }
            if (lane == 0) {
                cfinA[r0] = cA0; cfinA[r0 + 1] = cA1;
                cfinB[r0] = cB0; cfinB[r0 + 1] = cB1;
            }
        }
        __syncthreads();

        // 5. combine (gelu + residual, in regs) + LN partials -> pstat
        f32x4 oA0, oA1, oB0, oB1;
        {
#pragma unroll
            for (int reg = 0; reg < 4; ++reg) {
                int trow = cgq * 4 + reg;
                float cA = cfinA[trow], cB = cfinB[trow];
                int c0 = wv * 32 + m, c1 = c0 + 16;
                float v, g;
                v = dA0[reg] + cA; g = 0.5f * v * (1.0f + erff(v * 0.70710678118654752f));
                oA0[reg] = g + bf2f(*(const us*)((const char*)xlA + swz(trow, c0 >> 3) + (c0 & 7) * 2));
                v = dA1[reg] + cA; g = 0.5f * v * (1.0f + erff(v * 0.70710678118654752f));
                oA1[reg] = g + bf2f(*(const us*)((const char*)xlA + swz(trow, c1 >> 3) + (c1 & 7) * 2));
                v = dB0[reg] + cB; g = 0.5f * v * (1.0f + erff(v * 0.70710678118654752f));
                oB0[reg] = g + bf2f(*(const us*)((const char*)xlB + swz(trow, c0 >> 3) + (c0 & 7) * 2));
                v = dB1[reg] + cB; g = 0.5f * v * (1.0f + erff(v * 0.70710678118654752f));
                oB1[reg] = g + bf2f(*(const us*)((const char*)xlB + swz(trow, c1 >> 3) + (c1 & 7) * 2));
            }
#pragma unroll
            for (int reg = 0; reg < 4; ++reg) {
                float sA = oA0[reg] + oA1[reg];
                float qA = oA0[reg] * oA0[reg] + oA1[reg] * oA1[reg];
                float sB = oB0[reg] + oB1[reg];
                float qB = oB0[reg] * oB0[reg] + oB1[reg] * oB1[reg];
#pragma unroll
                for (int k = 1; k < 16; k <<= 1) {
                    sA += __shfl_xor(sA, k, 64); qA += __shfl_xor(qA, k, 64);
                    sB += __shfl_xor(sB, k, 64); qB += __shfl_xor(qB, k, 64);
                }
                if (m == 0) {
                    int row = cgq * 4 + reg;
                    int ia = ((0 * 8 + wv) * 16 + row) * 2;
                    int ib = ((1 * 8 + wv) * 16 + row) * 2;
                    pstat[ia] = sA; pstat[ia + 1] = qA;
                    pstat[ib] = sB; pstat[ib + 1] = qB;
                }
            }
        }
        __syncthreads();

        // 6. LN finalize (analytic double-LN at l==3) -> write xlA/xlB
        {
            const bool last = (l == 3);
#pragma unroll
            for (int reg = 0; reg < 4; ++reg) {
                int row = cgq * 4 + reg;
                float sA = 0.f, qA = 0.f, sB = 0.f, qB = 0.f;
#pragma unroll
                for (int w = 0; w < 8; ++w) {
                    sA += pstat[((0 * 8 + w) * 16 + row) * 2];
                    qA += pstat[((0 * 8 + w) * 16 + row) * 2 + 1];
                    sB += pstat[((1 * 8 + w) * 16 + row) * 2];
                    qB += pstat[((1 * 8 + w) * 16 + row) * 2 + 1];
                }
                float mnA = sA * (1.0f / HDIM);
                float varA = qA * (1.0f / HDIM) - mnA * mnA;
                float rsA = rsqrtf(varA + 1e-5f);
                float mnB = sB * (1.0f / HDIM);
                float varB = qB * (1.0f / HDIM) - mnB * mnB;
                float rsB = rsqrtf(varB + 1e-5f);
                if (last) {
                    float vzA = varA * rsA * rsA; rsA *= rsqrtf(vzA + 1e-5f);
                    float vzB = varB * rsB * rsB; rsB *= rsqrtf(vzB + 1e-5f);
                }
                int c0 = wv * 32 + m, c1 = c0 + 16;
                *(us*)((char*)xlA + swz(row, c0 >> 3) + (c0 & 7) * 2) = f2bf((oA0[reg] - mnA) * rsA);
                *(us*)((char*)xlA + swz(row, c1 >> 3) + (c1 & 7) * 2) = f2bf((oA1[reg] - mnA) * rsA);
                *(us*)((char*)xlB + swz(row, c0 >> 3) + (c0 & 7) * 2) = f2bf((oB0[reg] - mnB) * rsB);
                *(us*)((char*)xlB + swz(row, c1 >> 3) + (c1 & 7) * 2) = f2bf((oB1[reg] - mnB) * rsB);
            }
        }
        __syncthreads();

        if (l < 3) {
            {   // 7a. B-proj next layer: waves 0-3 tileA, 4-7 tileB
                const int tw = (wv < 4) ? wv : wv - 4;
                const us* xls = (wv < 4) ? xlA : xlB;
                const size_t gr = (wv < 4) ? growA : growB;
                f32x4 accb = z4;
                const us* B0 = Bm_bf + (size_t)(l + 1) * NDIM * HDIM + (size_t)(tw * 16 + m) * HDIM;
#pragma unroll
                for (int ks = 0; ks < 8; ++ks) {
                    s16x8 av = *(const s16x8*)((const char*)xls + swz(m, ks * 4 + cgq));
                    s16x8 bv = *(const s16x8*)(B0 + ks * 32 + cgq * 8);
                    accb = MFMA16(av, bv, accb, 0, 0, 0);
                }
#pragma unroll
                for (int reg = 0; reg < 4; ++reg)
                    st_mall(&bo[(gr + cgq * 4 + reg) * NDIM + tw * 16 + m], accb[reg]);
            }
            __syncthreads();    // drain
            if (tid == 0) flag_set(&flags[4 + (l + 1) * NTILE + tileA]);
            if (tid == 1) flag_set(&flags[4 + (l + 1) * NTILE + tileB]);
        } else {
            // 7b. out-GEMM both tiles
            f32x4 qA0 = z4, qA1 = z4, qB0 = z4, qB1 = z4;
            const us* W0 = Wout_bf + (size_t)(wv * 32 + m) * HDIM;
            const us* W1 = W0 + (size_t)16 * HDIM;
#pragma unroll
            for (int ks = 0; ks < 8; ++ks) {
                s16x8 avA = *(const s16x8*)((const char*)xlA + swz(m, ks * 4 + cgq));
                s16x8 avB = *(const s16x8*)((const char*)xlB + swz(m, ks * 4 + cgq));
                s16x8 w0 = *(const s16x8*)(W0 + ks * 32 + cgq * 8);
                s16x8 w1 = *(const s16x8*)(W1 + ks * 32 + cgq * 8);
                qA0 = MFMA16(avA, w0, qA0, 0, 0, 0);
                qA1 = MFMA16(avA, w1, qA1, 0, 0, 0);
                qB0 = MFMA16(avB, w0, qB0, 0, 0, 0);
                qB1 = MFMA16(avB, w1, qB1, 0, 0, 0);
            }
            const int h0c = wv * 32 + m, h1c = h0c + 16;
            float bo0 = bout[h0c], bo1 = bout[h1c];
#pragma unroll
            for (int reg = 0; reg < 4; ++reg) {
                int trow = cgq * 4 + reg;
                out[(growA + trow) * HDIM + h0c] = qA0[reg] + bo0;
                out[(growA + trow) * HDIM + h1c] = qA1[reg] + bo1;
                out[(growB + trow) * HDIM + h0c] = qB0[reg] + bo0;
                out[(growB + trow) * HDIM + h1c] = qB1[reg] + bo1;
            }
        }
    }
}

extern "C" void kernel_launch(void* const* d_in, const int* in_sizes, int n_in,
                              void* d_out, int out_size, void* d_ws, size_t ws_size,
                              hipStream_t stream) {
    (void)in_sizes; (void)n_in; (void)out_size; (void)ws_size;
    const float* x    = (const float*)d_in[0];
    const float* Win  = (const float*)d_in[1];
    const float* bin  = (const float*)d_in[2];
    const float* Wout = (const float*)d_in[3];
    const float* bout = (const float*)d_in[4];
    const float* A    = (const float*)d_in[5];
    const float* Bm   = (const float*)d_in[6];
    const float* Cm   = (const float*)d_in[7];
    const float* Dm   = (const float*)d_in[8];

    float* ws     = (float*)d_ws;
    float* wbuf   = ws;                           // 12288 f32, pad 16384
    float* cbar_g = ws + 16384;                   // 256, pad 1024
    float* wA8    = ws + 17408;                   // 4096
    float* biA    = ws + 21504;                   // 131072
    float* biB    = ws + 152576;                  // 131072
    unsigned* flags = (unsigned*)(ws + 283648);   // 516 u32, pad 1024
    us* Win_bf  = (us*)(ws + 284672);             // 65536 us
    us* Wout_bf = Win_bf + 65536;
    us* Bm_bf   = Wout_bf + 65536;
    us* Dm_bf   = Bm_bf + 65536;                  // 262144 us
    float* out  = (float*)d_out;

    k_prep<<<130, 256, 0, stream>>>(Win, Wout, Bm, Dm, Cm, A,
                                    Win_bf, Wout_bf, Bm_bf, Dm_bf, cbar_g, wA8, flags);
    k_fused<<<NWB + 1, 512, 0, stream>>>(x, bin, bout, A, wA8, cbar_g,
                                         Win_bf, Wout_bf, Bm_bf, Dm_bf,
                                         wbuf, biA, biB, flags, out);
}

// Round 15
// 76.005 us; speedup vs baseline: 2.9049x; 1.1567x over previous
//
#include <hip/hip_runtime.h>

#define TSEQ 512
#define HDIM 256
#define NDIM 64
#define LC   48        // conv truncation; tail ~0.909^48 ~ 2e-3 (threshold 0.1)
#define MT   16        // t-rows per work block
#define NWB  128       // work blocks; block 128 = W block

typedef __attribute__((ext_vector_type(4))) float  f32x4;
typedef __attribute__((ext_vector_type(8))) short  s16x8;
typedef __attribute__((ext_vector_type(4))) unsigned short u16x4;
typedef unsigned long long u64;
typedef unsigned short us;

#define MFMA16 __builtin_amdgcn_mfma_f32_16x16x32_bf16

__device__ __forceinline__ float lane_bcast(float v, int l) {
    return __int_as_float(__builtin_amdgcn_readlane(__float_as_int(v), l));
}
__device__ __forceinline__ us f2bf(float f) {
    unsigned u = __float_as_uint(f);
    u += 0x7fffu + ((u >> 16) & 1u);
    return (us)(u >> 16);
}
__device__ __forceinline__ float bf2f(us h) {
    return __uint_as_float(((unsigned)h) << 16);
}
__device__ __forceinline__ int swz(int row, int chunk) {   // 16B chunk in [16][256] bf16 tile
    return row * 512 + (((chunk) ^ (row & 7)) << 4);
}
__device__ __forceinline__ void st_mall(float* p, float v) {
    __hip_atomic_store(p, v, __ATOMIC_RELAXED, __HIP_MEMORY_SCOPE_AGENT);
}
__device__ __forceinline__ u64 ld_mall8(const u64* p) {
    return __hip_atomic_load(p, __ATOMIC_RELAXED, __HIP_MEMORY_SCOPE_AGENT);
}
__device__ __forceinline__ void flag_set(unsigned* f) {
    __hip_atomic_store(f, 1u, __ATOMIC_RELAXED, __HIP_MEMORY_SCOPE_AGENT);
}
__device__ __forceinline__ void flag_wait(const unsigned* f) {
    while (__hip_atomic_load(f, __ATOMIC_RELAXED, __HIP_MEMORY_SCOPE_AGENT) == 0u)
        __builtin_amdgcn_s_sleep(1);
}

// ============ k_prep: weights f32->bf16 (0..127), Cbar+flags (128), A2/A4/A8 (129) ========
__global__ void __launch_bounds__(256) k_prep(
    const float* __restrict__ Win, const float* __restrict__ Wout,
    const float* __restrict__ Bm, const float* __restrict__ Dm,
    const float* __restrict__ Cm, const float* __restrict__ A,
    us* __restrict__ Win_bf, us* __restrict__ Wout_bf,
    us* __restrict__ Bm_bf, us* __restrict__ Dm_bf,
    float* __restrict__ cbar_g, float* __restrict__ wA4, float* __restrict__ wA8,
    unsigned* __restrict__ flags)
{
    __shared__ __align__(16) float Pa[4096];
    __shared__ __align__(16) float Pb[4096];
    const int gid = blockIdx.x, tid = threadIdx.x;

    if (gid < 128) {
        for (int q = gid * 256 + tid; q < 114688; q += 32768) {
            const float* s; us* d; int off;
            if (q < 16384)      { s = Win;  d = Win_bf;  off = q; }
            else if (q < 32768) { s = Wout; d = Wout_bf; off = q - 16384; }
            else if (q < 49152) { s = Bm;   d = Bm_bf;   off = q - 32768; }
            else                { s = Dm;   d = Dm_bf;   off = q - 49152; }
            f32x4 v = ((const f32x4*)s)[off];
            u16x4 p; p[0] = f2bf(v[0]); p[1] = f2bf(v[1]); p[2] = f2bf(v[2]); p[3] = f2bf(v[3]);
            ((u16x4*)d)[off] = p;
        }
        return;
    }
    if (gid == 128) {
        for (int i = tid; i < 4 + 4 * NWB; i += 256)
            __hip_atomic_store(&flags[i], 0u, __ATOMIC_RELAXED, __HIP_MEMORY_SCOPE_AGENT);
        const int l = tid >> 6, n = tid & 63;
        const float* cp = Cm + (size_t)l * HDIM * NDIM + n;
        float s0 = 0.f, s1 = 0.f, s2 = 0.f, s3 = 0.f;
        for (int h = 0; h < HDIM; h += 4) {
            s0 += cp[(h + 0) * NDIM]; s1 += cp[(h + 1) * NDIM];
            s2 += cp[(h + 2) * NDIM]; s3 += cp[(h + 3) * NDIM];
        }
        cbar_g[tid] = ((s0 + s1) + (s2 + s3)) * (1.0f / HDIM);
        return;
    }
    // gid == 129: A2 (Pb), A4 (Pa), A8 (Pb after it2); export A4, A8
    for (int q = tid; q < 1024; q += 256) ((f32x4*)Pa)[q] = ((const f32x4*)A)[q];
    __syncthreads();
    const int r0 = (tid >> 3) * 2, c0 = (tid & 7) * 8;
    const f32x4 z4 = {0.f, 0.f, 0.f, 0.f};
#pragma unroll 1
    for (int it = 0; it < 3; ++it) {
        const float* S = (it & 1) ? Pb : Pa;
        float*       D = (it & 1) ? Pa : Pb;
        f32x4 s00 = z4, s01 = z4, s10 = z4, s11 = z4;
        for (int k = 0; k < 64; ++k) {
            float a0 = S[r0 * 64 + k], a1 = S[(r0 + 1) * 64 + k];
            f32x4 b0 = *(const f32x4*)(S + k * 64 + c0);
            f32x4 b1 = *(const f32x4*)(S + k * 64 + c0 + 4);
            s00 += a0 * b0; s01 += a0 * b1; s10 += a1 * b0; s11 += a1 * b1;
        }
        *(f32x4*)(D + r0 * 64 + c0) = s00;       *(f32x4*)(D + r0 * 64 + c0 + 4) = s01;
        *(f32x4*)(D + (r0 + 1) * 64 + c0) = s10; *(f32x4*)(D + (r0 + 1) * 64 + c0 + 4) = s11;
        __syncthreads();
    }
    for (int q = tid; q < 1024; q += 256) {
        ((f32x4*)wA4)[q] = ((const f32x4*)Pa)[q];   // A4
        ((f32x4*)wA8)[q] = ((const f32x4*)Pb)[q];   // A8
    }
}

// ============ k_fused ============
__global__ void __launch_bounds__(512, 2) k_fused(
    const float* __restrict__ x, const float* __restrict__ bin,
    const float* __restrict__ bout, const float* __restrict__ A,
    const float* __restrict__ wA4, const float* __restrict__ wA8,
    const float* __restrict__ cbar_g,
    const us* __restrict__ Win_bf, const us* __restrict__ Wout_bf,
    const us* __restrict__ Bm_bf, const us* __restrict__ Dm_bf,
    float* __restrict__ wbuf, float* __restrict__ BiA, float* __restrict__ BiB,
    unsigned* __restrict__ flags, float* __restrict__ out)
{
    __shared__ __align__(16) char smem[57344];
    // work-block layout
    us*    xl   = (us*)smem;                    //  8192 B [16][256] bf16 swz
    float* bwin = (float*)(smem + 8192);        // 16384 B [64][64]
    float* wlds = (float*)(smem + 24576);       // 12288 B [48][64]
    float* cfin = (float*)(smem + 36864);       //    64 B
    float* pstat = (float*)(smem + 36928);      //  1024 B [8][16][2]
    // W-block aliases
    float* As  = (float*)smem;                  // 16384 B
    float* A4s = (float*)(smem + 16384);        // 16384 B
    float* A8s = (float*)(smem + 32768);        // 16384 B
    float* uls = (float*)(smem + 49152);        //  8192 B [32][64]

    const int gid = blockIdx.x, tid = threadIdx.x;
    const int lane = tid & 63, wv = tid >> 6;
    const int m = lane & 15, cgq = lane >> 4;
    const f32x4 z4 = {0.f, 0.f, 0.f, 0.f};

    if (gid == NWB) {
        // ======== W block: seeds via A / A4 split (max 4 serial), chains over A8 ========
        for (int q = tid; q < 1024; q += 512) {
            ((f32x4*)As)[q]  = ((const f32x4*)A)[q];
            ((f32x4*)A4s)[q] = ((const f32x4*)wA4)[q];
            ((f32x4*)A8s)[q] = ((const f32x4*)wA8)[q];
        }
        __syncthreads();
        {   // seeds: wave w -> layer l = w>>1, half hf = w&1
            const int l = wv >> 1, hf = wv & 1;
            float u = cbar_g[l * 64 + lane];
            if (hf) {   // u = (A^T)^4 c via A4
                float p0 = 0.f, p1 = 0.f, p2 = 0.f, p3 = 0.f;
#pragma unroll
                for (int k = 0; k < 64; k += 4) {
                    p0 += A4s[(k + 0) * 64 + lane] * lane_bcast(u, k + 0);
                    p1 += A4s[(k + 1) * 64 + lane] * lane_bcast(u, k + 1);
                    p2 += A4s[(k + 2) * 64 + lane] * lane_bcast(u, k + 2);
                    p3 += A4s[(k + 3) * 64 + lane] * lane_bcast(u, k + 3);
                }
                u = (p0 + p1) + (p2 + p3);
            }
            uls[(l * 8 + hf * 4 + 0) * 64 + lane] = u;
#pragma unroll 1
            for (int s = 1; s < 4; ++s) {
                float p0 = 0.f, p1 = 0.f, p2 = 0.f, p3 = 0.f;
#pragma unroll
                for (int k = 0; k < 64; k += 4) {
                    p0 += As[(k + 0) * 64 + lane] * lane_bcast(u, k + 0);
                    p1 += As[(k + 1) * 64 + lane] * lane_bcast(u, k + 1);
                    p2 += As[(k + 2) * 64 + lane] * lane_bcast(u, k + 2);
                    p3 += As[(k + 3) * 64 + lane] * lane_bcast(u, k + 3);
                }
                u = (p0 + p1) + (p2 + p3);
                uls[(l * 8 + hf * 4 + s) * 64 + lane] = u;
            }
        }
        __syncthreads();
        {   // layer-0 chain first (parity wv), then flag[0]
            float u = uls[wv * 64 + lane];
#pragma unroll 1
            for (int k6 = 0; k6 < 6; ++k6) {
                st_mall(&wbuf[(size_t)(wv + 8 * k6) * 64 + lane], u);
                if (k6 < 5) {
                    float n0 = 0.f;
#pragma unroll
                    for (int k = 0; k < 64; ++k)
                        n0 += A8s[k * 64 + lane] * lane_bcast(u, k);
                    u = n0;
                }
            }
        }
        __syncthreads();
        if (tid == 0) flag_set(&flags[0]);
        {   // layers 1-3 chains interleaved
            float u1 = uls[(8 + wv) * 64 + lane];
            float u2 = uls[(16 + wv) * 64 + lane];
            float u3 = uls[(24 + wv) * 64 + lane];
#pragma unroll 1
            for (int k6 = 0; k6 < 6; ++k6) {
                const int j = wv + 8 * k6;
                st_mall(&wbuf[(size_t)(1 * LC + j) * 64 + lane], u1);
                st_mall(&wbuf[(size_t)(2 * LC + j) * 64 + lane], u2);
                st_mall(&wbuf[(size_t)(3 * LC + j) * 64 + lane], u3);
                if (k6 < 5) {
                    float n1 = 0.f, n2 = 0.f, n3 = 0.f;
#pragma unroll
                    for (int k = 0; k < 64; ++k) {
                        float a = A8s[k * 64 + lane];
                        n1 += a * lane_bcast(u1, k); n2 += a * lane_bcast(u2, k);
                        n3 += a * lane_bcast(u3, k);
                    }
                    u1 = n1; u2 = n2; u3 = n3;
                }
            }
        }
        __syncthreads();
        if (tid < 3) flag_set(&flags[1 + tid]);
        return;
    }

    // ======== work blocks: 16 t-rows, h resident in LDS across all layers ========
    const int b = gid >> 5, tb = gid & 31, t0 = tb * MT;
    const size_t grow = (size_t)(b * TSEQ + t0);

    {   // stage x (f32 -> bf16 swizzled LDS)
        const f32x4* gs = (const f32x4*)(x + grow * HDIM);
#pragma unroll
        for (int k = 0; k < 2; ++k) {
            int q = tid + k * 512;
            int row = q >> 6, c4 = q & 63;
            f32x4 v = gs[q];
            u16x4 pk; pk[0] = f2bf(v[0]); pk[1] = f2bf(v[1]); pk[2] = f2bf(v[2]); pk[3] = f2bf(v[3]);
            *(u16x4*)((char*)xl + swz(row, c4 >> 1) + (c4 & 1) * 8) = pk;
        }
    }
    __syncthreads();   // [F1]

    f32x4 hacc0, hacc1;
    {   // in-GEMM: h0 = x @ Win^T + bin
        f32x4 accA = z4, accB = z4;
        const us* W0 = Win_bf + (size_t)(wv * 32 + m) * HDIM;
        const us* W1 = W0 + (size_t)16 * HDIM;
#pragma unroll
        for (int ks = 0; ks < 8; ++ks) {
            s16x8 av = *(const s16x8*)((const char*)xl + swz(m, ks * 4 + cgq));
            s16x8 b0 = *(const s16x8*)(W0 + ks * 32 + cgq * 8);
            s16x8 b1 = *(const s16x8*)(W1 + ks * 32 + cgq * 8);
            accA = MFMA16(av, b0, accA, 0, 0, 0);
            accB = MFMA16(av, b1, accB, 0, 0, 0);
        }
        hacc0 = accA; hacc1 = accB;
    }
    __syncthreads();   // [F2] x reads done
    {   // write h0 -> xl
        const int h0c = wv * 32 + m, h1c = h0c + 16;
        float bi0 = bin[h0c], bi1 = bin[h1c];
#pragma unroll
        for (int reg = 0; reg < 4; ++reg) {
            int trow = cgq * 4 + reg;
            *(us*)((char*)xl + swz(trow, h0c >> 3) + (h0c & 7) * 2) = f2bf(hacc0[reg] + bi0);
            *(us*)((char*)xl + swz(trow, h1c >> 3) + (h1c & 7) * 2) = f2bf(hacc1[reg] + bi1);
        }
    }
    __syncthreads();   // [F3] h0 ready

    // ---------------- layer loop: 5 barriers per layer ----------------
#pragma unroll 1
    for (int l = 0; l < 4; ++l) {
        float* bufl = (l & 1) ? BiB : BiA;
        const us* Dl = Dm_bf + (size_t)l * HDIM * HDIM;

        // Phase A: B-proj^l (waves 0-3, first) + D-GEMM^l (all waves)
        if (wv < 4) {
            f32x4 accb = z4;
            const us* B0 = Bm_bf + (size_t)l * NDIM * HDIM + (size_t)(wv * 16 + m) * HDIM;
#pragma unroll
            for (int ks = 0; ks < 8; ++ks) {
                s16x8 av = *(const s16x8*)((const char*)xl + swz(m, ks * 4 + cgq));
                s16x8 bv = *(const s16x8*)(B0 + ks * 32 + cgq * 8);
                accb = MFMA16(av, bv, accb, 0, 0, 0);
            }
#pragma unroll
            for (int reg = 0; reg < 4; ++reg)
                st_mall(&bufl[(grow + cgq * 4 + reg) * NDIM + wv * 16 + m], accb[reg]);
        }
        f32x4 dA0 = z4, dA1 = z4;
        {
            const us* D0 = Dl + (size_t)(wv * 32 + m) * HDIM;
            const us* D1 = D0 + (size_t)16 * HDIM;
#pragma unroll
            for (int ks = 0; ks < 8; ++ks) {
                s16x8 av = *(const s16x8*)((const char*)xl + swz(m, ks * 4 + cgq));
                s16x8 b0 = *(const s16x8*)(D0 + ks * 32 + cgq * 8);
                s16x8 b1 = *(const s16x8*)(D1 + ks * 32 + cgq * 8);
                dA0 = MFMA16(av, b0, dA0, 0, 0, 0);
                dA1 = MFMA16(av, b1, dA1, 0, 0, 0);
            }
        }
        __syncthreads();   // [A] drains binp stores
        if (tid == 0) flag_set(&flags[4 + l * NWB + gid]);

        // wait: w flag (lane 3), neighbor binp tiles (lanes 0..2)
        {
            const unsigned* fp = nullptr;
            if (lane == 3) fp = &flags[l];
            else if (lane < 3 && (tb - 1 - (int)lane) >= 0) fp = &flags[4 + l * NWB + gid - 1 - lane];
            if (fp) flag_wait(fp);
        }

        // Phase B: stage w + binp window rows [t0-48, t0+15]
        {
            const u64* ws8 = (const u64*)(wbuf + (size_t)l * LC * NDIM);
            for (int q = tid; q < LC * NDIM / 2; q += 512)
                ((u64*)wlds)[q] = ld_mall8(&ws8[q]);
            const u64* bi8 = (const u64*)(bufl + (size_t)b * TSEQ * NDIM);
#pragma unroll
            for (int k = 0; k < 4; ++k) {
                int q = tid + k * 512;
                int r = q >> 5, cc = q & 31;
                int t = t0 - LC + r;
                ((u64*)bwin)[q] = (t >= 0) ? ld_mall8(&bi8[(size_t)t * 32 + cc]) : 0ull;
            }
        }
        __syncthreads();   // [B]

        {   // Phase C: conv, 2 rows/wave
            const int r0 = wv * 2;
            float c0 = 0.f, c1 = 0.f;
            float v0 = bwin[(LC - 1 + r0) * NDIM + lane];
            float v1 = bwin[(LC + r0) * NDIM + lane];
#pragma unroll
            for (int j = 0; j < LC; ++j) {
                float wj = wlds[j * NDIM + lane];
                c0 += wj * v0; c1 += wj * v1;
                v1 = v0;
                int nr = LC - 2 + r0 - j; nr = nr < 0 ? 0 : nr;
                v0 = bwin[nr * NDIM + lane];
            }
#pragma unroll
            for (int k = 1; k < 64; k <<= 1) {
                c0 += __shfl_xor(c0, k, 64); c1 += __shfl_xor(c1, k, 64);
            }
            if (lane == 0) { cfin[r0] = c0; cfin[r0 + 1] = c1; }
        }
        __syncthreads();   // [C]

        // Phase D: combine (gelu + residual, in regs) + LN partials -> pstat
        f32x4 o0, o1;
        {
            const int c0i = wv * 32 + m, c1i = c0i + 16;
#pragma unroll
            for (int reg = 0; reg < 4; ++reg) {
                int trow = cgq * 4 + reg;
                float cf = cfin[trow];
                float v, g;
                v = dA0[reg] + cf; g = 0.5f * v * (1.0f + erff(v * 0.70710678118654752f));
                o0[reg] = g + bf2f(*(const us*)((const char*)xl + swz(trow, c0i >> 3) + (c0i & 7) * 2));
                v = dA1[reg] + cf; g = 0.5f * v * (1.0f + erff(v * 0.70710678118654752f));
                o1[reg] = g + bf2f(*(const us*)((const char*)xl + swz(trow, c1i >> 3) + (c1i & 7) * 2));
            }
#pragma unroll
            for (int reg = 0; reg < 4; ++reg) {
                float s = o0[reg] + o1[reg];
                float q = o0[reg] * o0[reg] + o1[reg] * o1[reg];
#pragma unroll
                for (int k = 1; k < 16; k <<= 1) {
                    s += __shfl_xor(s, k, 64); q += __shfl_xor(q, k, 64);
                }
                if (m == 0) {
                    int row = cgq * 4 + reg;
                    int idx = (wv * 16 + row) * 2;
                    pstat[idx] = s; pstat[idx + 1] = q;
                }
            }
        }
        __syncthreads();   // [D]

        {   // Phase E: LN finalize (analytic double-LN at l==3) -> xl
            const bool last = (l == 3);
            const int c0i = wv * 32 + m, c1i = c0i + 16;
#pragma unroll
            for (int reg = 0; reg < 4; ++reg) {
                int row = cgq * 4 + reg;
                float s = 0.f, q = 0.f;
#pragma unroll
                for (int w = 0; w < 8; ++w) {
                    s += pstat[(w * 16 + row) * 2];
                    q += pstat[(w * 16 + row) * 2 + 1];
                }
                float mn = s * (1.0f / HDIM);
                float var = q * (1.0f / HDIM) - mn * mn;
                float rs = rsqrtf(var + 1e-5f);
                if (last) { float vz = var * rs * rs; rs *= rsqrtf(vz + 1e-5f); }
                *(us*)((char*)xl + swz(row, c0i >> 3) + (c0i & 7) * 2) = f2bf((o0[reg] - mn) * rs);
                *(us*)((char*)xl + swz(row, c1i >> 3) + (c1i & 7) * 2) = f2bf((o1[reg] - mn) * rs);
            }
        }
        __syncthreads();   // [E]
    }

    {   // out-GEMM: out = z2 @ Wout^T + bout
        f32x4 a2A = z4, a2B = z4;
        const us* W0 = Wout_bf + (size_t)(wv * 32 + m) * HDIM;
        const us* W1 = W0 + (size_t)16 * HDIM;
#pragma unroll
        for (int ks = 0; ks < 8; ++ks) {
            s16x8 av = *(const s16x8*)((const char*)xl + swz(m, ks * 4 + cgq));
            s16x8 b0 = *(const s16x8*)(W0 + ks * 32 + cgq * 8);
            s16x8 b1 = *(const s16x8*)(W1 + ks * 32 + cgq * 8);
            a2A = MFMA16(av, b0, a2A, 0, 0, 0);
            a2B = MFMA16(av, b1, a2B, 0, 0, 0);
        }
        const int h0c = wv * 32 + m, h1c = h0c + 16;
        float bo0 = bout[h0c], bo1 = bout[h1c];
#pragma unroll
        for (int reg = 0; reg < 4; ++reg) {
            int trow = cgq * 4 + reg;
            out[(grow + trow) * HDIM + h0c] = a2A[reg] + bo0;
            out[(grow + trow) * HDIM + h1c] = a2B[reg] + bo1;
        }
    }
}

extern "C" void kernel_launch(void* const* d_in, const int* in_sizes, int n_in,
                              void* d_out, int out_size, void* d_ws, size_t ws_size,
                              hipStream_t stream) {
    (void)in_sizes; (void)n_in; (void)out_size; (void)ws_size;
    const float* x    = (const float*)d_in[0];
    const float* Win  = (const float*)d_in[1];
    const float* bin  = (const float*)d_in[2];
    const float* Wout = (const float*)d_in[3];
    const float* bout = (const float*)d_in[4];
    const float* A    = (const float*)d_in[5];
    const float* Bm   = (const float*)d_in[6];
    const float* Cm   = (const float*)d_in[7];
    const float* Dm   = (const float*)d_in[8];

    float* ws     = (float*)d_ws;
    float* wbuf   = ws;                           // 12288 f32, pad 16384
    float* cbar_g = ws + 16384;                   // 256, pad 1024
    float* wA8    = ws + 17408;                   // 4096
    float* wA4    = ws + 21504;                   // 4096
    float* biA    = ws + 25600;                   // 131072
    float* biB    = ws + 156672;                  // 131072
    unsigned* flags = (unsigned*)(ws + 287744);   // 516 u32, pad 1024
    us* Win_bf  = (us*)(ws + 288768);             // 65536 us
    us* Wout_bf = Win_bf + 65536;
    us* Bm_bf   = Wout_bf + 65536;
    us* Dm_bf   = Bm_bf + 65536;                  // 262144 us
    float* out  = (float*)d_out;

    k_prep<<<130, 256, 0, stream>>>(Win, Wout, Bm, Dm, Cm, A,
                                    Win_bf, Wout_bf, Bm_bf, Dm_bf, cbar_g, wA4, wA8, flags);
    k_fused<<<NWB + 1, 512, 0, stream>>>(x, bin, bout, A, wA4, wA8, cbar_g,
                                         Win_bf, Wout_bf, Bm_bf, Dm_bf,
                                         wbuf, biA, biB, flags, out);
}